// Round 1
// baseline (4593.532 us; speedup 1.0000x reference)
//
#include <hip/hip_runtime.h>
#include <math.h>

__device__ __forceinline__ float sigf(float x) { return 1.f / (1.f + expf(-x)); }

// ---------------------------------------------------------------------------
// out[r][c] = relu(sum_k in[r][k]*W[k][c] + b[c]),  c in [0,64)
// ---------------------------------------------------------------------------
__global__ __launch_bounds__(256)
void rowmat_relu_kernel(const float* __restrict__ in, const float* __restrict__ W,
                        const float* __restrict__ b, float* __restrict__ out,
                        int R, int K)
{
    const int lane = threadIdx.x & 63;
    const int row  = blockIdx.x * 4 + (threadIdx.x >> 6);
    if (row >= R) return;
    const float* inr = in + (size_t)row * K;
    float acc = b[lane];
    for (int k = 0; k < K; ++k)
        acc = fmaf(inr[k], W[(size_t)k * 64 + lane], acc);
    out[(size_t)row * 64 + lane] = fmaxf(acc, 0.f);
}

// ---------------------------------------------------------------------------
// Fused NNConv message:
//   msg[e][o] = sum_i h[src[e]][i] * ( sum_k t[e][k]*eW2[k][i*64+o] + eb2[i*64+o] )
// accumulated atomically into msum[dst[e]][o].
// Block: 64 threads, 64 edges; 8x8 register tile per thread.
// ---------------------------------------------------------------------------
__global__ __launch_bounds__(64)
void msg_kernel(const float* __restrict__ t, const float* __restrict__ h,
                const int* __restrict__ src, const int* __restrict__ dst,
                const float* __restrict__ eW2, const float* __restrict__ eb2,
                float* __restrict__ msum, int E)
{
    __shared__ __align__(16) float tT[64 * 68];   // tT[k*68 + e]
    __shared__ __align__(16) float hT[64 * 68];   // hT[i*68 + e]
    __shared__ __align__(16) float wS[64 * 64];   // wS[k*64 + o]
    __shared__ __align__(16) float ebS[64];

    const int tid = threadIdx.x;
    const int e0  = blockIdx.x * 64;

    // stage t and h[src] transposed (coalesced global reads; one-time 8-way LDS
    // write conflict from the +4 pad is negligible vs the 64 i-step main loop)
    for (int idx = tid; idx < 4096; idx += 64) {
        int e = idx >> 6, c = idx & 63;           // c == tid
        int ee = e0 + e;
        float tv = 0.f, hv = 0.f;
        if (ee < E) {
            tv = t[(size_t)ee * 64 + c];
            hv = h[(size_t)src[ee] * 64 + c];
        }
        tT[c * 68 + e] = tv;
        hT[c * 68 + e] = hv;
    }

    const int rt = (tid & 7) * 8;   // 8 edges
    const int ct = (tid >> 3) * 8;  // 8 output cols

    float acc[8][8] = {};

    for (int i = 0; i < 64; ++i) {
        __syncthreads();
        const float* w_src = eW2 + (size_t)i * 64;
        for (int j = tid; j < 1024; j += 64) {
            int k = j >> 4, o4 = (j & 15) << 2;
            *(float4*)&wS[k * 64 + o4] = *(const float4*)&w_src[(size_t)k * 4096 + o4];
        }
        ebS[tid] = eb2[i * 64 + tid];
        __syncthreads();

        float4 h4a = *(const float4*)&hT[i * 68 + rt];
        float4 h4b = *(const float4*)&hT[i * 68 + rt + 4];
        float hv[8] = {h4a.x, h4a.y, h4a.z, h4a.w, h4b.x, h4b.y, h4b.z, h4b.w};
        float4 e4a = *(const float4*)&ebS[ct];
        float4 e4b = *(const float4*)&ebS[ct + 4];
        float eb[8] = {e4a.x, e4a.y, e4a.z, e4a.w, e4b.x, e4b.y, e4b.z, e4b.w};
        #pragma unroll
        for (int a = 0; a < 8; ++a)
            #pragma unroll
            for (int q = 0; q < 8; ++q)
                acc[a][q] = fmaf(hv[a], eb[q], acc[a][q]);

        #pragma unroll 4
        for (int k = 0; k < 64; ++k) {
            float4 t4a = *(const float4*)&tT[k * 68 + rt];
            float4 t4b = *(const float4*)&tT[k * 68 + rt + 4];
            float4 w4a = *(const float4*)&wS[k * 64 + ct];
            float4 w4b = *(const float4*)&wS[k * 64 + ct + 4];
            float u[8] = {hv[0] * t4a.x, hv[1] * t4a.y, hv[2] * t4a.z, hv[3] * t4a.w,
                          hv[4] * t4b.x, hv[5] * t4b.y, hv[6] * t4b.z, hv[7] * t4b.w};
            float w[8] = {w4a.x, w4a.y, w4a.z, w4a.w, w4b.x, w4b.y, w4b.z, w4b.w};
            #pragma unroll
            for (int a = 0; a < 8; ++a)
                #pragma unroll
                for (int q = 0; q < 8; ++q)
                    acc[a][q] = fmaf(u[a], w[q], acc[a][q]);
        }
    }

    #pragma unroll
    for (int a = 0; a < 8; ++a) {
        int ee = e0 + rt + a;
        if (ee < E) {
            int d = dst[ee];
            #pragma unroll
            for (int q = 0; q < 8; ++q)
                atomicAdd(&msum[(size_t)d * 64 + ct + q], acc[a][q]);
        }
    }
}

// ---------------------------------------------------------------------------
// Fused GRU: m = relu(msum + conv_b); h = GRU(m, h) in-place.
// Block: 256 threads, 64 rows; per-thread 4 rows x (4 cols x 3 gates) x {i,h}.
// ---------------------------------------------------------------------------
__global__ __launch_bounds__(256)
void gru_kernel(const float* __restrict__ msum, float* __restrict__ h,
                const float* __restrict__ Wi, const float* __restrict__ Wh,
                const float* __restrict__ bi, const float* __restrict__ bh,
                const float* __restrict__ conv_b, int N)
{
    __shared__ __align__(16) float mT[64 * 68];   // mT[k*68 + r]
    __shared__ __align__(16) float hT[64 * 68];

    const int tid  = threadIdx.x;
    const int row0 = blockIdx.x * 64;

    for (int idx = tid; idx < 4096; idx += 256) {
        int r = idx >> 6, k = idx & 63;
        int row = row0 + r;
        float mv = 0.f, hv = 0.f;
        if (row < N) {
            mv = fmaxf(msum[(size_t)row * 64 + k] + conv_b[k], 0.f);
            hv = h[(size_t)row * 64 + k];
        }
        mT[k * 68 + r] = mv;
        hT[k * 68 + r] = hv;
    }
    __syncthreads();

    const int r0 = (tid & 15) * 4;
    const int c0 = (tid >> 4) * 4;

    float ai[3][4][4] = {};
    float ah[3][4][4] = {};

    for (int k = 0; k < 64; ++k) {
        float4 m4 = *(const float4*)&mT[k * 68 + r0];
        float4 h4 = *(const float4*)&hT[k * 68 + r0];
        float mv[4] = {m4.x, m4.y, m4.z, m4.w};
        float hv[4] = {h4.x, h4.y, h4.z, h4.w};
        const float* wik = Wi + (size_t)k * 192 + c0;
        const float* whk = Wh + (size_t)k * 192 + c0;
        #pragma unroll
        for (int g = 0; g < 3; ++g) {
            float4 wi4 = *(const float4*)&wik[g * 64];
            float4 wh4 = *(const float4*)&whk[g * 64];
            float wi[4] = {wi4.x, wi4.y, wi4.z, wi4.w};
            float wh[4] = {wh4.x, wh4.y, wh4.z, wh4.w};
            #pragma unroll
            for (int r = 0; r < 4; ++r)
                #pragma unroll
                for (int c = 0; c < 4; ++c) {
                    ai[g][r][c] = fmaf(mv[r], wi[c], ai[g][r][c]);
                    ah[g][r][c] = fmaf(hv[r], wh[c], ah[g][r][c]);
                }
        }
    }

    #pragma unroll
    for (int r = 0; r < 4; ++r) {
        int row = row0 + r0 + r;
        if (row >= N) continue;
        float o4[4];
        #pragma unroll
        for (int c = 0; c < 4; ++c) {
            int cc = c0 + c;
            float rg = sigf(ai[0][r][c] + bi[cc]       + ah[0][r][c] + bh[cc]);
            float zg = sigf(ai[1][r][c] + bi[64 + cc]  + ah[1][r][c] + bh[64 + cc]);
            float ng = tanhf(ai[2][r][c] + bi[128 + cc] + rg * (ah[2][r][c] + bh[128 + cc]));
            float hold = hT[cc * 68 + r0 + r];
            o4[c] = (1.f - zg) * ng + zg * hold;
        }
        float4 st = {o4[0], o4[1], o4[2], o4[3]};
        *(float4*)&h[(size_t)row * 64 + c0] = st;
    }
}

// ---------------------------------------------------------------------------
// Fused LSTM layer: gates = x@Wi + h@Wh + b; update c,h in place.
// Block: 256 threads, 64 rows; per-thread 4 rows x (4 cols x 4 gates).
// ---------------------------------------------------------------------------
__global__ __launch_bounds__(256)
void lstm_kernel(const float* __restrict__ x, int K1,
                 const float* __restrict__ Wi, const float* __restrict__ Wh,
                 const float* __restrict__ b,
                 float* __restrict__ hsl, float* __restrict__ csl, int R)
{
    __shared__ __align__(16) float xT[128 * 68];
    __shared__ __align__(16) float hT[64 * 68];

    const int tid  = threadIdx.x;
    const int row0 = blockIdx.x * 64;

    for (int idx = tid; idx < 64 * K1; idx += 256) {
        int r = (K1 == 128) ? (idx >> 7) : (idx >> 6);
        int k = idx & (K1 - 1);
        int row = row0 + r;
        xT[k * 68 + r] = (row < R) ? x[(size_t)row * K1 + k] : 0.f;
    }
    for (int idx = tid; idx < 4096; idx += 256) {
        int r = idx >> 6, k = idx & 63;
        int row = row0 + r;
        hT[k * 68 + r] = (row < R) ? hsl[(size_t)row * 64 + k] : 0.f;
    }
    __syncthreads();

    const int r0 = (tid & 15) * 4;
    const int c0 = (tid >> 4) * 4;

    float acc[4][4][4] = {};

    for (int k = 0; k < K1; ++k) {
        float4 x4 = *(const float4*)&xT[k * 68 + r0];
        float xv[4] = {x4.x, x4.y, x4.z, x4.w};
        const float* wik = Wi + (size_t)k * 256 + c0;
        #pragma unroll
        for (int g = 0; g < 4; ++g) {
            float4 w4 = *(const float4*)&wik[g * 64];
            float w[4] = {w4.x, w4.y, w4.z, w4.w};
            #pragma unroll
            for (int r = 0; r < 4; ++r)
                #pragma unroll
                for (int c = 0; c < 4; ++c)
                    acc[g][r][c] = fmaf(xv[r], w[c], acc[g][r][c]);
        }
    }
    for (int k = 0; k < 64; ++k) {
        float4 h4 = *(const float4*)&hT[k * 68 + r0];
        float hv[4] = {h4.x, h4.y, h4.z, h4.w};
        const float* whk = Wh + (size_t)k * 256 + c0;
        #pragma unroll
        for (int g = 0; g < 4; ++g) {
            float4 w4 = *(const float4*)&whk[g * 64];
            float w[4] = {w4.x, w4.y, w4.z, w4.w};
            #pragma unroll
            for (int r = 0; r < 4; ++r)
                #pragma unroll
                for (int c = 0; c < 4; ++c)
                    acc[g][r][c] = fmaf(hv[r], w[c], acc[g][r][c]);
        }
    }

    #pragma unroll
    for (int r = 0; r < 4; ++r) {
        int row = row0 + r0 + r;
        if (row >= R) continue;
        float cn[4], hn[4];
        #pragma unroll
        for (int c = 0; c < 4; ++c) {
            int cc = c0 + c;
            float ig = sigf(acc[0][r][c] + b[cc]);
            float fg = sigf(acc[1][r][c] + b[64 + cc]);
            float gg = tanhf(acc[2][r][c] + b[128 + cc]);
            float og = sigf(acc[3][r][c] + b[192 + cc]);
            float cold = csl[(size_t)row * 64 + cc];
            float cv = fg * cold + ig * gg;
            cn[c] = cv;
            hn[c] = og * tanhf(cv);
        }
        float4 cst = {cn[0], cn[1], cn[2], cn[3]};
        float4 hst = {hn[0], hn[1], hn[2], hn[3]};
        *(float4*)&csl[(size_t)row * 64 + c0] = cst;
        *(float4*)&hsl[(size_t)row * 64 + c0] = hst;
    }
}

// ---------------------------------------------------------------------------
// Per-graph softmax attention readout: q_star[g] = [q, sum_n alpha_n h_n]
// One 64-thread block (one wave) per graph; 25 contiguous nodes per graph.
// ---------------------------------------------------------------------------
__global__ __launch_bounds__(64)
void attn_kernel(const float* __restrict__ h, const float* __restrict__ q,
                 float* __restrict__ q_star)
{
    const int g    = blockIdx.x;
    const int lane = threadIdx.x;
    __shared__ float qs[64];
    __shared__ float hl[25 * 65];
    __shared__ float als[32];

    qs[lane] = q[(size_t)g * 64 + lane];
    for (int idx = lane; idx < 25 * 64; idx += 64) {
        int n = idx >> 6, d = idx & 63;
        hl[n * 65 + d] = h[((size_t)g * 25 + n) * 64 + d];
    }
    __syncthreads();

    float ev = -1e30f;
    if (lane < 25) {
        float acc = 0.f;
        for (int d = 0; d < 64; ++d) acc = fmaf(hl[lane * 65 + d], qs[d], acc);
        ev = acc;
    }
    float mx = ev;
    #pragma unroll
    for (int off = 32; off; off >>= 1) mx = fmaxf(mx, __shfl_xor(mx, off, 64));
    float ex = (lane < 25) ? expf(ev - mx) : 0.f;
    float sm = ex;
    #pragma unroll
    for (int off = 32; off; off >>= 1) sm += __shfl_xor(sm, off, 64);
    if (lane < 25) als[lane] = ex / sm;
    __syncthreads();

    float rdt = 0.f;
    #pragma unroll
    for (int n = 0; n < 25; ++n) rdt = fmaf(als[n], hl[n * 65 + lane], rdt);

    q_star[(size_t)g * 128 + lane]      = qs[lane];
    q_star[(size_t)g * 128 + 64 + lane] = rdt;
}

// ---------------------------------------------------------------------------
// Head: out[g] = sigmoid( relu(q_star @ pW + pb) @ fW + fb )
// ---------------------------------------------------------------------------
__global__ __launch_bounds__(64)
void predict_kernel(const float* __restrict__ q_star, const float* __restrict__ pW,
                    const float* __restrict__ pb, const float* __restrict__ fW,
                    const float* __restrict__ fb, float* __restrict__ out)
{
    const int g    = blockIdx.x;
    const int lane = threadIdx.x;
    __shared__ float xs[128];
    xs[lane]      = q_star[(size_t)g * 128 + lane];
    xs[64 + lane] = q_star[(size_t)g * 128 + 64 + lane];
    __syncthreads();
    float acc = pb[lane];
    for (int k = 0; k < 128; ++k) acc = fmaf(xs[k], pW[(size_t)k * 64 + lane], acc);
    float part = fmaxf(acc, 0.f) * fW[lane];
    #pragma unroll
    for (int off = 32; off; off >>= 1) part += __shfl_xor(part, off, 64);
    if (lane == 0) out[g] = 1.f / (1.f + expf(-(part + fb[0])));
}

// ---------------------------------------------------------------------------
extern "C" void kernel_launch(void* const* d_in, const int* in_sizes, int n_in,
                              void* d_out, int out_size, void* d_ws, size_t ws_size,
                              hipStream_t stream)
{
    const float* n_feats = (const float*)d_in[0];
    const float* e_feats = (const float*)d_in[1];
    const int*   src     = (const int*)d_in[2];
    const int*   dst     = (const int*)d_in[3];
    const float* proj_W  = (const float*)d_in[5];
    const float* proj_b  = (const float*)d_in[6];
    const float* eW1     = (const float*)d_in[7];
    const float* eb1     = (const float*)d_in[8];
    const float* eW2     = (const float*)d_in[9];
    const float* eb2     = (const float*)d_in[10];
    const float* conv_b  = (const float*)d_in[11];
    const float* gWi     = (const float*)d_in[12];
    const float* gWh     = (const float*)d_in[13];
    const float* gbi     = (const float*)d_in[14];
    const float* gbh     = (const float*)d_in[15];
    const float* lWi0    = (const float*)d_in[16];
    const float* lWh0    = (const float*)d_in[17];
    const float* lb0     = (const float*)d_in[18];
    const float* lWi1    = (const float*)d_in[19];
    const float* lWh1    = (const float*)d_in[20];
    const float* lb1     = (const float*)d_in[21];
    const float* lWi2    = (const float*)d_in[22];
    const float* lWh2    = (const float*)d_in[23];
    const float* lb2     = (const float*)d_in[24];
    const float* pW      = (const float*)d_in[25];
    const float* pb      = (const float*)d_in[26];
    const float* fW      = (const float*)d_in[27];
    const float* fb      = (const float*)d_in[28];

    const int N = in_sizes[0] / 74;   // 25000
    const int E = in_sizes[1] / 12;   // 50000
    const int G = out_size;           // 1000

    float* ws    = (float*)d_ws;
    float* h     = ws;                         // N*64
    float* msum  = h + (size_t)N * 64;         // N*64
    float* t     = msum + (size_t)N * 64;      // E*64
    float* hs0   = t + (size_t)E * 64;         // G*64 each below
    float* hs1   = hs0 + (size_t)G * 64;
    float* hs2   = hs1 + (size_t)G * 64;
    float* cs0   = hs2 + (size_t)G * 64;
    float* cs1   = cs0 + (size_t)G * 64;
    float* cs2   = cs1 + (size_t)G * 64;
    float* qstar = cs2 + (size_t)G * 64;       // G*128

    // node projection (GRU hidden init == h) and edge-net first layer
    rowmat_relu_kernel<<<(N + 3) / 4, 256, 0, stream>>>(n_feats, proj_W, proj_b, h, N, 74);
    rowmat_relu_kernel<<<(E + 3) / 4, 256, 0, stream>>>(e_feats, eW1, eb1, t, E, 12);

    // 3 rounds of message passing + GRU
    for (int it = 0; it < 3; ++it) {
        hipMemsetAsync(msum, 0, (size_t)N * 64 * sizeof(float), stream);
        msg_kernel<<<(E + 63) / 64, 64, 0, stream>>>(t, h, src, dst, eW2, eb2, msum, E);
        gru_kernel<<<(N + 63) / 64, 256, 0, stream>>>(msum, h, gWi, gWh, gbi, gbh, conv_b, N);
    }

    // Set2Set: zero hs/cs/q_star (contiguous), then 3 iterations
    hipMemsetAsync(hs0, 0, (size_t)(6 * G * 64 + G * 128) * sizeof(float), stream);
    for (int it = 0; it < 3; ++it) {
        lstm_kernel<<<(G + 63) / 64, 256, 0, stream>>>(qstar, 128, lWi0, lWh0, lb0, hs0, cs0, G);
        lstm_kernel<<<(G + 63) / 64, 256, 0, stream>>>(hs0,    64,  lWi1, lWh1, lb1, hs1, cs1, G);
        lstm_kernel<<<(G + 63) / 64, 256, 0, stream>>>(hs1,    64,  lWi2, lWh2, lb2, hs2, cs2, G);
        attn_kernel<<<G, 64, 0, stream>>>(h, hs2, qstar);
    }

    predict_kernel<<<G, 64, 0, stream>>>(qstar, pW, pb, fW, fb, (float*)d_out);
}

// Round 2
// 831.256 us; speedup vs baseline: 5.5260x; 5.5260x over previous
//
#include <hip/hip_runtime.h>
#include <math.h>

__device__ __forceinline__ float sigf(float x) { return 1.f / (1.f + expf(-x)); }

typedef __attribute__((ext_vector_type(8)))  short short8v;
typedef __attribute__((ext_vector_type(16))) float f32x16;

__device__ __forceinline__ unsigned short f2bf(float x) {
    union { __bf16 b; unsigned short u; } c; c.b = (__bf16)x; return c.u;
}

// ---------------------------------------------------------------------------
// out[r][c] = relu(sum_k in[r][k]*W[k][c] + b[c]),  c in [0,64)
// ---------------------------------------------------------------------------
__global__ __launch_bounds__(256)
void rowmat_relu_kernel(const float* __restrict__ in, const float* __restrict__ W,
                        const float* __restrict__ b, float* __restrict__ out,
                        int R, int K)
{
    const int lane = threadIdx.x & 63;
    const int row  = blockIdx.x * 4 + (threadIdx.x >> 6);
    if (row >= R) return;
    const float* inr = in + (size_t)row * K;
    float acc = b[lane];
    for (int k = 0; k < K; ++k)
        acc = fmaf(inr[k], W[(size_t)k * 64 + lane], acc);
    out[(size_t)row * 64 + lane] = fmaxf(acc, 0.f);
}

// ---------------------------------------------------------------------------
// One-time weight prep: build bf16, pre-swizzled, chunk-major staging of
//   M[j][o], j in [0,4160):  j<4096 -> eW2_flat[j*64+o]  (j = k*64+i)
//                            j>=4096 -> eb2[(j-4096)*64+o]   (bias chunk, t=1)
// Layout: 65 chunks x 8192B. Within chunk: 16B slot (o,seg) at byte
//   (o*128 + seg*16) ^ ((o&7)<<4), holding M[kc*64+seg*8+m][o], m=0..7 (bf16).
// This makes block staging a LINEAR coalesced copy and ds_read_b128
// B-fragment reads <=4-way bank-conflicted.
// ---------------------------------------------------------------------------
__global__ __launch_bounds__(256)
void prep_w_kernel(const float* __restrict__ eW2, const float* __restrict__ eb2,
                   unsigned short* __restrict__ w_staged)
{
    int slot = blockIdx.x * 256 + threadIdx.x;     // 65*512 slots
    if (slot >= 65 * 512) return;
    int kc  = slot >> 9;
    int s   = slot & 511;
    int o   = s >> 3, seg = s & 7;
    unsigned int packed[4];
    #pragma unroll
    for (int p = 0; p < 4; ++p) {
        int j0 = kc * 64 + seg * 8 + p * 2;
        float v0 = (j0     < 4096) ? eW2[(size_t)j0 * 64 + o]       : eb2[(size_t)(j0 - 4096) * 64 + o];
        float v1 = (j0 + 1 < 4096) ? eW2[(size_t)(j0 + 1) * 64 + o] : eb2[(size_t)(j0 + 1 - 4096) * 64 + o];
        packed[p] = (unsigned int)f2bf(v0) | ((unsigned int)f2bf(v1) << 16);
    }
    int dstb = ((o * 128) + seg * 16) ^ ((o & 7) << 4);
    uint4 st = {packed[0], packed[1], packed[2], packed[3]};
    *(uint4*)((char*)w_staged + (size_t)kc * 8192 + dstb) = st;
}

// ---------------------------------------------------------------------------
// MFMA NNConv message:
//   msg[e][o] = sum_{kc=0..64} sum_{i} (t[e][kc] or 1)*h[src[e]][i] * M[kc*64+i][o]
// Block: 256 thr / 4 waves, 64 edges x 64 outs; wave (wm,wn) owns 32x32 tile.
// A built in registers (t-scalar x resident f32 h), B double-buffered in LDS.
// Accumulate into msum via atomics.
// ---------------------------------------------------------------------------
__global__ __launch_bounds__(256, 4)
void msg_mfma_kernel(const float* __restrict__ t, const float* __restrict__ h,
                     const int* __restrict__ src, const int* __restrict__ dst,
                     const unsigned short* __restrict__ w_staged,
                     float* __restrict__ msum, int E)
{
    __shared__ __align__(16) float tS[64 * 68];               // [k][e+pad]
    __shared__ __align__(16) unsigned short bbuf[2][4096];    // 2 x 8KB chunks

    const int tid  = threadIdx.x;
    const int lane = tid & 63;
    const int wave = tid >> 6;
    const int wm   = wave & 1, wn = wave >> 1;
    const int e0   = blockIdx.x * 64;

    // stage t tile transposed: tS[k][e]
    #pragma unroll
    for (int p = 0; p < 4; ++p) {
        int lin = tid + p * 256;                 // 0..1023
        int e = lin >> 4, k0 = (lin & 15) << 2;
        int ee = e0 + e;
        float4 v = make_float4(0.f, 0.f, 0.f, 0.f);
        if (ee < E) v = *(const float4*)&t[(size_t)ee * 64 + k0];
        tS[(k0 + 0) * 68 + e] = v.x;
        tS[(k0 + 1) * 68 + e] = v.y;
        tS[(k0 + 2) * 68 + e] = v.z;
        tS[(k0 + 3) * 68 + e] = v.w;
    }

    // resident h row (f32): edge = e0 + wm*32 + (lane&31); this lane's K-half koff
    const int erow = wm * 32 + (lane & 31);
    const int ee   = e0 + erow;
    const int sidx = (ee < E) ? src[ee] : 0;
    const float* hrow = h + (size_t)sidx * 64;
    const int koff = (lane >> 5) * 8;
    float Hf[4][8];
    #pragma unroll
    for (int s = 0; s < 4; ++s) {
        float4 a = *(const float4*)&hrow[s * 16 + koff];
        float4 b = *(const float4*)&hrow[s * 16 + koff + 4];
        Hf[s][0] = a.x; Hf[s][1] = a.y; Hf[s][2] = a.z; Hf[s][3] = a.w;
        Hf[s][4] = b.x; Hf[s][5] = b.y; Hf[s][6] = b.z; Hf[s][7] = b.w;
    }

    // prologue: stage chunk 0
    const uint4* wsrc = (const uint4*)w_staged;
    uint4 stg0 = wsrc[tid];
    uint4 stg1 = wsrc[256 + tid];
    ((uint4*)bbuf[0])[tid]       = stg0;
    ((uint4*)bbuf[0])[256 + tid] = stg1;

    f32x16 acc;
    #pragma unroll
    for (int r = 0; r < 16; ++r) acc[r] = 0.f;

    const int colg = wn * 32 + (lane & 31);
    const int bbase = (colg * 128) ^ ((colg & 7) << 4);

    for (int kc = 0; kc < 65; ++kc) {
        const int cur = kc & 1;
        if (kc < 64) {  // issue next chunk's loads (in flight across compute)
            stg0 = wsrc[(size_t)(kc + 1) * 512 + tid];
            stg1 = wsrc[(size_t)(kc + 1) * 512 + 256 + tid];
        }
        __syncthreads();   // bbuf[cur] ready

        const float tv = (kc < 64) ? tS[kc * 68 + erow] : 1.0f;
        const char* bb = (const char*)bbuf[cur];
        #pragma unroll
        for (int s = 0; s < 4; ++s) {
            union { short8v v; __bf16 b[8]; } af;
            #pragma unroll
            for (int m = 0; m < 8; ++m)
                af.b[m] = (__bf16)(tv * Hf[s][m]);
            short8v bf = *(const short8v*)(bb + (bbase + s * 32 + (lane >> 5) * 16));
            acc = __builtin_amdgcn_mfma_f32_32x32x16_bf16(af.v, bf, acc, 0, 0, 0);
        }
        __syncthreads();   // all waves done reading bbuf[cur^1]
        if (kc < 64) {
            const int nxt = (kc + 1) & 1;
            ((uint4*)bbuf[nxt])[tid]       = stg0;
            ((uint4*)bbuf[nxt])[256 + tid] = stg1;
        }
    }

    // epilogue: C/D layout col=lane&31, row=(r&3)+8*(r>>2)+4*(lane>>5)
    #pragma unroll
    for (int r = 0; r < 16; ++r) {
        const int row  = (r & 3) + 8 * (r >> 2) + 4 * (lane >> 5);
        const int edge = e0 + wm * 32 + row;
        if (edge < E)
            atomicAdd(&msum[(size_t)dst[edge] * 64 + colg], acc[r]);
    }
}

// ---------------------------------------------------------------------------
// Fused GRU: m = relu(msum + conv_b); h = GRU(m, h) in-place.
// ---------------------------------------------------------------------------
__global__ __launch_bounds__(256)
void gru_kernel(const float* __restrict__ msum, float* __restrict__ h,
                const float* __restrict__ Wi, const float* __restrict__ Wh,
                const float* __restrict__ bi, const float* __restrict__ bh,
                const float* __restrict__ conv_b, int N)
{
    __shared__ __align__(16) float mT[64 * 68];
    __shared__ __align__(16) float hT[64 * 68];

    const int tid  = threadIdx.x;
    const int row0 = blockIdx.x * 64;

    for (int idx = tid; idx < 4096; idx += 256) {
        int r = idx >> 6, k = idx & 63;
        int row = row0 + r;
        float mv = 0.f, hv = 0.f;
        if (row < N) {
            mv = fmaxf(msum[(size_t)row * 64 + k] + conv_b[k], 0.f);
            hv = h[(size_t)row * 64 + k];
        }
        mT[k * 68 + r] = mv;
        hT[k * 68 + r] = hv;
    }
    __syncthreads();

    const int r0 = (tid & 15) * 4;
    const int c0 = (tid >> 4) * 4;

    float ai[3][4][4] = {};
    float ah[3][4][4] = {};

    for (int k = 0; k < 64; ++k) {
        float4 m4 = *(const float4*)&mT[k * 68 + r0];
        float4 h4 = *(const float4*)&hT[k * 68 + r0];
        float mv[4] = {m4.x, m4.y, m4.z, m4.w};
        float hv[4] = {h4.x, h4.y, h4.z, h4.w};
        const float* wik = Wi + (size_t)k * 192 + c0;
        const float* whk = Wh + (size_t)k * 192 + c0;
        #pragma unroll
        for (int g = 0; g < 3; ++g) {
            float4 wi4 = *(const float4*)&wik[g * 64];
            float4 wh4 = *(const float4*)&whk[g * 64];
            float wi[4] = {wi4.x, wi4.y, wi4.z, wi4.w};
            float wh[4] = {wh4.x, wh4.y, wh4.z, wh4.w};
            #pragma unroll
            for (int r = 0; r < 4; ++r)
                #pragma unroll
                for (int c = 0; c < 4; ++c) {
                    ai[g][r][c] = fmaf(mv[r], wi[c], ai[g][r][c]);
                    ah[g][r][c] = fmaf(hv[r], wh[c], ah[g][r][c]);
                }
        }
    }

    #pragma unroll
    for (int r = 0; r < 4; ++r) {
        int row = row0 + r0 + r;
        if (row >= N) continue;
        float o4[4];
        #pragma unroll
        for (int c = 0; c < 4; ++c) {
            int cc = c0 + c;
            float rg = sigf(ai[0][r][c] + bi[cc]        + ah[0][r][c] + bh[cc]);
            float zg = sigf(ai[1][r][c] + bi[64 + cc]   + ah[1][r][c] + bh[64 + cc]);
            float ng = tanhf(ai[2][r][c] + bi[128 + cc] + rg * (ah[2][r][c] + bh[128 + cc]));
            float hold = hT[cc * 68 + r0 + r];
            o4[c] = (1.f - zg) * ng + zg * hold;
        }
        float4 st = {o4[0], o4[1], o4[2], o4[3]};
        *(float4*)&h[(size_t)row * 64 + c0] = st;
    }
}

// ---------------------------------------------------------------------------
// Fused LSTM layer: gates = x@Wi + h@Wh + b; update c,h in place.
// ---------------------------------------------------------------------------
__global__ __launch_bounds__(256)
void lstm_kernel(const float* __restrict__ x, int K1,
                 const float* __restrict__ Wi, const float* __restrict__ Wh,
                 const float* __restrict__ b,
                 float* __restrict__ hsl, float* __restrict__ csl, int R)
{
    __shared__ __align__(16) float xT[128 * 68];
    __shared__ __align__(16) float hT[64 * 68];

    const int tid  = threadIdx.x;
    const int row0 = blockIdx.x * 64;

    for (int idx = tid; idx < 64 * K1; idx += 256) {
        int r = (K1 == 128) ? (idx >> 7) : (idx >> 6);
        int k = idx & (K1 - 1);
        int row = row0 + r;
        xT[k * 68 + r] = (row < R) ? x[(size_t)row * K1 + k] : 0.f;
    }
    for (int idx = tid; idx < 4096; idx += 256) {
        int r = idx >> 6, k = idx & 63;
        int row = row0 + r;
        hT[k * 68 + r] = (row < R) ? hsl[(size_t)row * 64 + k] : 0.f;
    }
    __syncthreads();

    const int r0 = (tid & 15) * 4;
    const int c0 = (tid >> 4) * 4;

    float acc[4][4][4] = {};

    for (int k = 0; k < K1; ++k) {
        float4 x4 = *(const float4*)&xT[k * 68 + r0];
        float xv[4] = {x4.x, x4.y, x4.z, x4.w};
        const float* wik = Wi + (size_t)k * 256 + c0;
        #pragma unroll
        for (int g = 0; g < 4; ++g) {
            float4 w4 = *(const float4*)&wik[g * 64];
            float w[4] = {w4.x, w4.y, w4.z, w4.w};
            #pragma unroll
            for (int r = 0; r < 4; ++r)
                #pragma unroll
                for (int c = 0; c < 4; ++c)
                    acc[g][r][c] = fmaf(xv[r], w[c], acc[g][r][c]);
        }
    }
    for (int k = 0; k < 64; ++k) {
        float4 h4 = *(const float4*)&hT[k * 68 + r0];
        float hv[4] = {h4.x, h4.y, h4.z, h4.w};
        const float* whk = Wh + (size_t)k * 256 + c0;
        #pragma unroll
        for (int g = 0; g < 4; ++g) {
            float4 w4 = *(const float4*)&whk[g * 64];
            float w[4] = {w4.x, w4.y, w4.z, w4.w};
            #pragma unroll
            for (int r = 0; r < 4; ++r)
                #pragma unroll
                for (int c = 0; c < 4; ++c)
                    acc[g][r][c] = fmaf(hv[r], w[c], acc[g][r][c]);
        }
    }

    #pragma unroll
    for (int r = 0; r < 4; ++r) {
        int row = row0 + r0 + r;
        if (row >= R) continue;
        float cn[4], hn[4];
        #pragma unroll
        for (int c = 0; c < 4; ++c) {
            int cc = c0 + c;
            float ig = sigf(acc[0][r][c] + b[cc]);
            float fg = sigf(acc[1][r][c] + b[64 + cc]);
            float gg = tanhf(acc[2][r][c] + b[128 + cc]);
            float og = sigf(acc[3][r][c] + b[192 + cc]);
            float cold = csl[(size_t)row * 64 + cc];
            float cv = fg * cold + ig * gg;
            cn[c] = cv;
            hn[c] = og * tanhf(cv);
        }
        float4 cst = {cn[0], cn[1], cn[2], cn[3]};
        float4 hst = {hn[0], hn[1], hn[2], hn[3]};
        *(float4*)&csl[(size_t)row * 64 + c0] = cst;
        *(float4*)&hsl[(size_t)row * 64 + c0] = hst;
    }
}

// ---------------------------------------------------------------------------
// Per-graph softmax attention readout: q_star[g] = [q, sum_n alpha_n h_n]
// ---------------------------------------------------------------------------
__global__ __launch_bounds__(64)
void attn_kernel(const float* __restrict__ h, const float* __restrict__ q,
                 float* __restrict__ q_star)
{
    const int g    = blockIdx.x;
    const int lane = threadIdx.x;
    __shared__ float qs[64];
    __shared__ float hl[25 * 65];
    __shared__ float als[32];

    qs[lane] = q[(size_t)g * 64 + lane];
    for (int idx = lane; idx < 25 * 64; idx += 64) {
        int n = idx >> 6, d = idx & 63;
        hl[n * 65 + d] = h[((size_t)g * 25 + n) * 64 + d];
    }
    __syncthreads();

    float ev = -1e30f;
    if (lane < 25) {
        float acc = 0.f;
        for (int d = 0; d < 64; ++d) acc = fmaf(hl[lane * 65 + d], qs[d], acc);
        ev = acc;
    }
    float mx = ev;
    #pragma unroll
    for (int off = 32; off; off >>= 1) mx = fmaxf(mx, __shfl_xor(mx, off, 64));
    float ex = (lane < 25) ? expf(ev - mx) : 0.f;
    float sm = ex;
    #pragma unroll
    for (int off = 32; off; off >>= 1) sm += __shfl_xor(sm, off, 64);
    if (lane < 25) als[lane] = ex / sm;
    __syncthreads();

    float rdt = 0.f;
    #pragma unroll
    for (int n = 0; n < 25; ++n) rdt = fmaf(als[n], hl[n * 65 + lane], rdt);

    q_star[(size_t)g * 128 + lane]      = qs[lane];
    q_star[(size_t)g * 128 + 64 + lane] = rdt;
}

// ---------------------------------------------------------------------------
// Head: out[g] = sigmoid( relu(q_star @ pW + pb) @ fW + fb )
// ---------------------------------------------------------------------------
__global__ __launch_bounds__(64)
void predict_kernel(const float* __restrict__ q_star, const float* __restrict__ pW,
                    const float* __restrict__ pb, const float* __restrict__ fW,
                    const float* __restrict__ fb, float* __restrict__ out)
{
    const int g    = blockIdx.x;
    const int lane = threadIdx.x;
    __shared__ float xs[128];
    xs[lane]      = q_star[(size_t)g * 128 + lane];
    xs[64 + lane] = q_star[(size_t)g * 128 + 64 + lane];
    __syncthreads();
    float acc = pb[lane];
    for (int k = 0; k < 128; ++k) acc = fmaf(xs[k], pW[(size_t)k * 64 + lane], acc);
    float part = fmaxf(acc, 0.f) * fW[lane];
    #pragma unroll
    for (int off = 32; off; off >>= 1) part += __shfl_xor(part, off, 64);
    if (lane == 0) out[g] = 1.f / (1.f + expf(-(part + fb[0])));
}

// ---------------------------------------------------------------------------
extern "C" void kernel_launch(void* const* d_in, const int* in_sizes, int n_in,
                              void* d_out, int out_size, void* d_ws, size_t ws_size,
                              hipStream_t stream)
{
    const float* n_feats = (const float*)d_in[0];
    const float* e_feats = (const float*)d_in[1];
    const int*   src     = (const int*)d_in[2];
    const int*   dst     = (const int*)d_in[3];
    const float* proj_W  = (const float*)d_in[5];
    const float* proj_b  = (const float*)d_in[6];
    const float* eW1     = (const float*)d_in[7];
    const float* eb1     = (const float*)d_in[8];
    const float* eW2     = (const float*)d_in[9];
    const float* eb2     = (const float*)d_in[10];
    const float* conv_b  = (const float*)d_in[11];
    const float* gWi     = (const float*)d_in[12];
    const float* gWh     = (const float*)d_in[13];
    const float* gbi     = (const float*)d_in[14];
    const float* gbh     = (const float*)d_in[15];
    const float* lWi0    = (const float*)d_in[16];
    const float* lWh0    = (const float*)d_in[17];
    const float* lb0     = (const float*)d_in[18];
    const float* lWi1    = (const float*)d_in[19];
    const float* lWh1    = (const float*)d_in[20];
    const float* lb1     = (const float*)d_in[21];
    const float* lWi2    = (const float*)d_in[22];
    const float* lWh2    = (const float*)d_in[23];
    const float* lb2     = (const float*)d_in[24];
    const float* pW      = (const float*)d_in[25];
    const float* pb      = (const float*)d_in[26];
    const float* fW      = (const float*)d_in[27];
    const float* fb      = (const float*)d_in[28];

    const int N = in_sizes[0] / 74;   // 25000
    const int E = in_sizes[1] / 12;   // 50000
    const int G = out_size;           // 1000

    float* ws    = (float*)d_ws;
    float* h     = ws;                         // N*64
    float* msum  = h + (size_t)N * 64;         // N*64
    float* t     = msum + (size_t)N * 64;      // E*64
    float* hs0   = t + (size_t)E * 64;         // G*64 each below
    float* hs1   = hs0 + (size_t)G * 64;
    float* hs2   = hs1 + (size_t)G * 64;
    float* cs0   = hs2 + (size_t)G * 64;
    float* cs1   = cs0 + (size_t)G * 64;
    float* cs2   = cs1 + (size_t)G * 64;
    float* qstar = cs2 + (size_t)G * 64;       // G*128
    unsigned short* w_staged = (unsigned short*)(qstar + (size_t)G * 128); // 65*8192 B

    // one-time: weight staging (bf16, swizzled, chunk-major)
    prep_w_kernel<<<130, 256, 0, stream>>>(eW2, eb2, w_staged);

    // node projection (GRU hidden init == h) and edge-net first layer
    rowmat_relu_kernel<<<(N + 3) / 4, 256, 0, stream>>>(n_feats, proj_W, proj_b, h, N, 74);
    rowmat_relu_kernel<<<(E + 3) / 4, 256, 0, stream>>>(e_feats, eW1, eb1, t, E, 12);

    // 3 rounds of message passing + GRU
    for (int it = 0; it < 3; ++it) {
        hipMemsetAsync(msum, 0, (size_t)N * 64 * sizeof(float), stream);
        msg_mfma_kernel<<<(E + 63) / 64, 256, 0, stream>>>(t, h, src, dst, w_staged, msum, E);
        gru_kernel<<<(N + 63) / 64, 256, 0, stream>>>(msum, h, gWi, gWh, gbi, gbh, conv_b, N);
    }

    // Set2Set: zero hs/cs/q_star (contiguous), then 3 iterations
    hipMemsetAsync(hs0, 0, (size_t)(6 * G * 64 + G * 128) * sizeof(float), stream);
    for (int it = 0; it < 3; ++it) {
        lstm_kernel<<<(G + 63) / 64, 256, 0, stream>>>(qstar, 128, lWi0, lWh0, lb0, hs0, cs0, G);
        lstm_kernel<<<(G + 63) / 64, 256, 0, stream>>>(hs0,    64,  lWi1, lWh1, lb1, hs1, cs1, G);
        lstm_kernel<<<(G + 63) / 64, 256, 0, stream>>>(hs1,    64,  lWi2, lWh2, lb2, hs2, cs2, G);
        attn_kernel<<<G, 64, 0, stream>>>(h, hs2, qstar);
    }

    predict_kernel<<<G, 64, 0, stream>>>(qstar, pW, pb, fW, fb, (float*)d_out);
}

// Round 3
// 548.402 us; speedup vs baseline: 8.3762x; 1.5158x over previous
//
#include <hip/hip_runtime.h>
#include <math.h>

__device__ __forceinline__ float sigf(float x) { return 1.f / (1.f + expf(-x)); }

typedef __attribute__((ext_vector_type(8)))  short short8v;
typedef __attribute__((ext_vector_type(16))) float f32x16;

__device__ __forceinline__ unsigned short f2bf(float x) {
    union { __bf16 b; unsigned short u; } c; c.b = (__bf16)x; return c.u;
}

// ---------------------------------------------------------------------------
// out[r][c] = relu(sum_k in[r][k]*W[k][c] + b[c]),  c in [0,64)
// ---------------------------------------------------------------------------
__global__ __launch_bounds__(256)
void rowmat_relu_kernel(const float* __restrict__ in, const float* __restrict__ W,
                        const float* __restrict__ b, float* __restrict__ out,
                        int R, int K)
{
    const int lane = threadIdx.x & 63;
    const int row  = blockIdx.x * 4 + (threadIdx.x >> 6);
    if (row >= R) return;
    const float* inr = in + (size_t)row * K;
    float acc = b[lane];
    for (int k = 0; k < K; ++k)
        acc = fmaf(inr[k], W[(size_t)k * 64 + lane], acc);
    out[(size_t)row * 64 + lane] = fmaxf(acc, 0.f);
}

// ---------------------------------------------------------------------------
// One-time weight prep: bf16, pre-swizzled, chunk-major staging of
//   M[j][o], j in [0,4160):  j<4096 -> eW2_flat[j*64+o]; j>=4096 -> eb2 row.
// Chunk kc (64 j's): 16B slot (o,seg) at byte (o*128+seg*16)^((o&7)<<4).
// ---------------------------------------------------------------------------
__global__ __launch_bounds__(256)
void prep_w_kernel(const float* __restrict__ eW2, const float* __restrict__ eb2,
                   unsigned short* __restrict__ w_staged)
{
    int slot = blockIdx.x * 256 + threadIdx.x;     // 65*512 slots
    if (slot >= 65 * 512) return;
    int kc  = slot >> 9;
    int s   = slot & 511;
    int o   = s >> 3, seg = s & 7;
    unsigned int packed[4];
    #pragma unroll
    for (int p = 0; p < 4; ++p) {
        int j0 = kc * 64 + seg * 8 + p * 2;
        float v0 = (j0     < 4096) ? eW2[(size_t)j0 * 64 + o]       : eb2[(size_t)(j0 - 4096) * 64 + o];
        float v1 = (j0 + 1 < 4096) ? eW2[(size_t)(j0 + 1) * 64 + o] : eb2[(size_t)(j0 + 1 - 4096) * 64 + o];
        packed[p] = (unsigned int)f2bf(v0) | ((unsigned int)f2bf(v1) << 16);
    }
    int dstb = ((o * 128) + seg * 16) ^ ((o & 7) << 4);
    uint4 st = {packed[0], packed[1], packed[2], packed[3]};
    *(uint4*)((char*)w_staged + (size_t)kc * 8192 + dstb) = st;
}

// ---------------------------------------------------------------------------
// MFMA NNConv message (unchanged from round 2):
//   msg[e][o] = sum_{kc} sum_i (t[e][kc] or 1)*h[src[e]][i] * M[kc*64+i][o]
// ---------------------------------------------------------------------------
__global__ __launch_bounds__(256, 4)
void msg_mfma_kernel(const float* __restrict__ t, const float* __restrict__ h,
                     const int* __restrict__ src, const int* __restrict__ dst,
                     const unsigned short* __restrict__ w_staged,
                     float* __restrict__ msum, int E)
{
    __shared__ __align__(16) float tS[64 * 68];               // [k][e+pad]
    __shared__ __align__(16) unsigned short bbuf[2][4096];    // 2 x 8KB chunks

    const int tid  = threadIdx.x;
    const int lane = tid & 63;
    const int wave = tid >> 6;
    const int wm   = wave & 1, wn = wave >> 1;
    const int e0   = blockIdx.x * 64;

    #pragma unroll
    for (int p = 0; p < 4; ++p) {
        int lin = tid + p * 256;
        int e = lin >> 4, k0 = (lin & 15) << 2;
        int ee = e0 + e;
        float4 v = make_float4(0.f, 0.f, 0.f, 0.f);
        if (ee < E) v = *(const float4*)&t[(size_t)ee * 64 + k0];
        tS[(k0 + 0) * 68 + e] = v.x;
        tS[(k0 + 1) * 68 + e] = v.y;
        tS[(k0 + 2) * 68 + e] = v.z;
        tS[(k0 + 3) * 68 + e] = v.w;
    }

    const int erow = wm * 32 + (lane & 31);
    const int ee   = e0 + erow;
    const int sidx = (ee < E) ? src[ee] : 0;
    const float* hrow = h + (size_t)sidx * 64;
    const int koff = (lane >> 5) * 8;
    float Hf[4][8];
    #pragma unroll
    for (int s = 0; s < 4; ++s) {
        float4 a = *(const float4*)&hrow[s * 16 + koff];
        float4 b = *(const float4*)&hrow[s * 16 + koff + 4];
        Hf[s][0] = a.x; Hf[s][1] = a.y; Hf[s][2] = a.z; Hf[s][3] = a.w;
        Hf[s][4] = b.x; Hf[s][5] = b.y; Hf[s][6] = b.z; Hf[s][7] = b.w;
    }

    const uint4* wsrc = (const uint4*)w_staged;
    uint4 stg0 = wsrc[tid];
    uint4 stg1 = wsrc[256 + tid];
    ((uint4*)bbuf[0])[tid]       = stg0;
    ((uint4*)bbuf[0])[256 + tid] = stg1;

    f32x16 acc;
    #pragma unroll
    for (int r = 0; r < 16; ++r) acc[r] = 0.f;

    const int colg = wn * 32 + (lane & 31);
    const int bbase = (colg * 128) ^ ((colg & 7) << 4);

    for (int kc = 0; kc < 65; ++kc) {
        const int cur = kc & 1;
        if (kc < 64) {
            stg0 = wsrc[(size_t)(kc + 1) * 512 + tid];
            stg1 = wsrc[(size_t)(kc + 1) * 512 + 256 + tid];
        }
        __syncthreads();

        const float tv = (kc < 64) ? tS[kc * 68 + erow] : 1.0f;
        const char* bb = (const char*)bbuf[cur];
        #pragma unroll
        for (int s = 0; s < 4; ++s) {
            union { short8v v; __bf16 b[8]; } af;
            #pragma unroll
            for (int m = 0; m < 8; ++m)
                af.b[m] = (__bf16)(tv * Hf[s][m]);
            short8v bf = *(const short8v*)(bb + (bbase + s * 32 + (lane >> 5) * 16));
            acc = __builtin_amdgcn_mfma_f32_32x32x16_bf16(af.v, bf, acc, 0, 0, 0);
        }
        __syncthreads();
        if (kc < 64) {
            const int nxt = (kc + 1) & 1;
            ((uint4*)bbuf[nxt])[tid]       = stg0;
            ((uint4*)bbuf[nxt])[256 + tid] = stg1;
        }
    }

    #pragma unroll
    for (int r = 0; r < 16; ++r) {
        const int row  = (r & 3) + 8 * (r >> 2) + 4 * (lane >> 5);
        const int edge = e0 + wm * 32 + row;
        if (edge < E)
            atomicAdd(&msum[(size_t)dst[edge] * 64 + colg], acc[r]);
    }
}

// ---------------------------------------------------------------------------
// Fused GRU v2: 32 rows/block (782 blocks -> ~3 blocks/CU, 12 waves/CU).
// m = relu(msum + conv_b); h = GRU(m, h) in-place.
// Thread: 2 rows x 4 cols x 3 gates x {i,h}. Weight loads coalesced
// (lanes 0..15 cover one contiguous 256B line per gate).
// ---------------------------------------------------------------------------
__global__ __launch_bounds__(256)
void gru_kernel(const float* __restrict__ msum, float* __restrict__ h,
                const float* __restrict__ Wi, const float* __restrict__ Wh,
                const float* __restrict__ bi, const float* __restrict__ bh,
                const float* __restrict__ conv_b, int N)
{
    __shared__ __align__(16) float mT[64 * 34];
    __shared__ __align__(16) float hT[64 * 34];

    const int tid  = threadIdx.x;
    const int row0 = blockIdx.x * 32;

    #pragma unroll
    for (int p = 0; p < 2; ++p) {
        int idx = tid + p * 256;          // 0..511
        int r = idx >> 4, k4 = (idx & 15) << 2;
        int row = row0 + r;
        float4 mv = make_float4(0.f, 0.f, 0.f, 0.f);
        float4 hv = make_float4(0.f, 0.f, 0.f, 0.f);
        if (row < N) {
            mv = *(const float4*)&msum[(size_t)row * 64 + k4];
            hv = *(const float4*)&h[(size_t)row * 64 + k4];
        }
        float4 cb = *(const float4*)&conv_b[k4];
        mT[(k4 + 0) * 34 + r] = fmaxf(mv.x + cb.x, 0.f);
        mT[(k4 + 1) * 34 + r] = fmaxf(mv.y + cb.y, 0.f);
        mT[(k4 + 2) * 34 + r] = fmaxf(mv.z + cb.z, 0.f);
        mT[(k4 + 3) * 34 + r] = fmaxf(mv.w + cb.w, 0.f);
        hT[(k4 + 0) * 34 + r] = hv.x;
        hT[(k4 + 1) * 34 + r] = hv.y;
        hT[(k4 + 2) * 34 + r] = hv.z;
        hT[(k4 + 3) * 34 + r] = hv.w;
    }
    __syncthreads();

    const int r0 = (tid >> 4) * 2;    // 0..30
    const int c0 = (tid & 15) * 4;    // 0..60

    float ai[3][2][4] = {};
    float ah[3][2][4] = {};

    for (int k = 0; k < 64; ++k) {
        float m0 = mT[k * 34 + r0], m1 = mT[k * 34 + r0 + 1];
        float h0 = hT[k * 34 + r0], h1 = hT[k * 34 + r0 + 1];
        const float* wik = Wi + (size_t)k * 192 + c0;
        const float* whk = Wh + (size_t)k * 192 + c0;
        #pragma unroll
        for (int g = 0; g < 3; ++g) {
            float4 wi4 = *(const float4*)&wik[g * 64];
            float4 wh4 = *(const float4*)&whk[g * 64];
            float wi[4] = {wi4.x, wi4.y, wi4.z, wi4.w};
            float wh[4] = {wh4.x, wh4.y, wh4.z, wh4.w};
            #pragma unroll
            for (int c = 0; c < 4; ++c) {
                ai[g][0][c] = fmaf(m0, wi[c], ai[g][0][c]);
                ai[g][1][c] = fmaf(m1, wi[c], ai[g][1][c]);
                ah[g][0][c] = fmaf(h0, wh[c], ah[g][0][c]);
                ah[g][1][c] = fmaf(h1, wh[c], ah[g][1][c]);
            }
        }
    }

    #pragma unroll
    for (int r = 0; r < 2; ++r) {
        int row = row0 + r0 + r;
        if (row >= N) continue;
        float o4[4];
        #pragma unroll
        for (int c = 0; c < 4; ++c) {
            int cc = c0 + c;
            float rg = sigf(ai[0][r][c] + bi[cc]        + ah[0][r][c] + bh[cc]);
            float zg = sigf(ai[1][r][c] + bi[64 + cc]   + ah[1][r][c] + bh[64 + cc]);
            float ng = tanhf(ai[2][r][c] + bi[128 + cc] + rg * (ah[2][r][c] + bh[128 + cc]));
            float hold = hT[cc * 34 + r0 + r];
            o4[c] = (1.f - zg) * ng + zg * hold;
        }
        float4 st = {o4[0], o4[1], o4[2], o4[3]};
        *(float4*)&h[(size_t)row * 64 + c0] = st;
    }
}

// ---------------------------------------------------------------------------
// Fully fused Set2Set (3 iters x 3-layer LSTM + attention) + predict head.
// One 256-thread block per graph; all state in LDS; no cross-graph coupling.
// Thread j owns gate column j (coalesced weight reads, L2-hot weights).
// ---------------------------------------------------------------------------
__global__ __launch_bounds__(256)
void set2set_kernel(const float* __restrict__ h,
                    const float* __restrict__ lWi0, const float* __restrict__ lWh0, const float* __restrict__ lb0,
                    const float* __restrict__ lWi1, const float* __restrict__ lWh1, const float* __restrict__ lb1,
                    const float* __restrict__ lWi2, const float* __restrict__ lWh2, const float* __restrict__ lb2,
                    const float* __restrict__ pW, const float* __restrict__ pb,
                    const float* __restrict__ fW, const float* __restrict__ fb,
                    float* __restrict__ out)
{
    const int g   = blockIdx.x;
    const int tid = threadIdx.x;

    __shared__ float hl[25 * 65];
    __shared__ float hs[3][64], cs[3][64];
    __shared__ float qstar[128];
    __shared__ float gates[256];
    __shared__ float als[32];

    for (int idx = tid; idx < 25 * 64; idx += 256) {
        int n = idx >> 6, d = idx & 63;
        hl[n * 65 + d] = h[((size_t)g * 25 + n) * 64 + d];
    }
    if (tid < 128) qstar[tid] = 0.f;
    if (tid < 64) {
        #pragma unroll
        for (int l = 0; l < 3; ++l) { hs[l][tid] = 0.f; cs[l][tid] = 0.f; }
    }
    __syncthreads();

    const float* Wis[3] = {lWi0, lWi1, lWi2};
    const float* Whs[3] = {lWh0, lWh1, lWh2};
    const float* bs[3]  = {lb0, lb1, lb2};

    for (int it = 0; it < 3; ++it) {
        #pragma unroll
        for (int l = 0; l < 3; ++l) {
            float acc = bs[l][tid];
            if (l == 0) {
                #pragma unroll 8
                for (int k = 0; k < 128; ++k)
                    acc = fmaf(qstar[k], lWi0[(size_t)k * 256 + tid], acc);
            } else {
                const float* x  = hs[l - 1];
                const float* Wi = Wis[l];
                #pragma unroll 8
                for (int k = 0; k < 64; ++k)
                    acc = fmaf(x[k], Wi[(size_t)k * 256 + tid], acc);
            }
            const float* Wh = Whs[l];
            #pragma unroll 8
            for (int k = 0; k < 64; ++k)
                acc = fmaf(hs[l][k], Wh[(size_t)k * 256 + tid], acc);
            gates[tid] = acc;
            __syncthreads();
            if (tid < 64) {
                float ig = sigf(gates[tid]);
                float fg = sigf(gates[64 + tid]);
                float gg = tanhf(gates[128 + tid]);
                float og = sigf(gates[192 + tid]);
                float cv = fg * cs[l][tid] + ig * gg;
                cs[l][tid] = cv;
                hs[l][tid] = og * tanhf(cv);
            }
            __syncthreads();
        }
        // attention over this graph's 25 nodes; q = hs[2]
        float ev = -1e30f;
        if (tid < 25) {
            float acc = 0.f;
            for (int d = 0; d < 64; ++d)
                acc = fmaf(hl[tid * 65 + d], hs[2][d], acc);
            ev = acc;
        }
        if (tid < 64) {
            float mx = ev;
            #pragma unroll
            for (int off = 16; off; off >>= 1) mx = fmaxf(mx, __shfl_xor(mx, off, 32));
            float ex = (tid < 25) ? expf(ev - mx) : 0.f;
            float sm = ex;
            #pragma unroll
            for (int off = 16; off; off >>= 1) sm += __shfl_xor(sm, off, 32);
            if (tid < 25) als[tid] = ex / sm;
        }
        __syncthreads();
        if (tid < 64) {
            float rdt = 0.f;
            #pragma unroll
            for (int n = 0; n < 25; ++n) rdt = fmaf(als[n], hl[n * 65 + tid], rdt);
            qstar[tid]      = hs[2][tid];
            qstar[64 + tid] = rdt;
        }
        __syncthreads();
    }

    // predict head: out = sigmoid(relu(qstar@pW+pb)@fW + fb)
    if (tid < 64) {
        float acc = pb[tid];
        #pragma unroll 8
        for (int k = 0; k < 128; ++k)
            acc = fmaf(qstar[k], pW[(size_t)k * 64 + tid], acc);
        float part = fmaxf(acc, 0.f) * fW[tid];
        #pragma unroll
        for (int off = 32; off; off >>= 1) part += __shfl_xor(part, off, 64);
        if (tid == 0) out[g] = 1.f / (1.f + expf(-(part + fb[0])));
    }
}

// ---------------------------------------------------------------------------
extern "C" void kernel_launch(void* const* d_in, const int* in_sizes, int n_in,
                              void* d_out, int out_size, void* d_ws, size_t ws_size,
                              hipStream_t stream)
{
    const float* n_feats = (const float*)d_in[0];
    const float* e_feats = (const float*)d_in[1];
    const int*   src     = (const int*)d_in[2];
    const int*   dst     = (const int*)d_in[3];
    const float* proj_W  = (const float*)d_in[5];
    const float* proj_b  = (const float*)d_in[6];
    const float* eW1     = (const float*)d_in[7];
    const float* eb1     = (const float*)d_in[8];
    const float* eW2     = (const float*)d_in[9];
    const float* eb2     = (const float*)d_in[10];
    const float* conv_b  = (const float*)d_in[11];
    const float* gWi     = (const float*)d_in[12];
    const float* gWh     = (const float*)d_in[13];
    const float* gbi     = (const float*)d_in[14];
    const float* gbh     = (const float*)d_in[15];
    const float* lWi0    = (const float*)d_in[16];
    const float* lWh0    = (const float*)d_in[17];
    const float* lb0     = (const float*)d_in[18];
    const float* lWi1    = (const float*)d_in[19];
    const float* lWh1    = (const float*)d_in[20];
    const float* lb1     = (const float*)d_in[21];
    const float* lWi2    = (const float*)d_in[22];
    const float* lWh2    = (const float*)d_in[23];
    const float* lb2     = (const float*)d_in[24];
    const float* pW      = (const float*)d_in[25];
    const float* pb      = (const float*)d_in[26];
    const float* fW      = (const float*)d_in[27];
    const float* fb      = (const float*)d_in[28];

    const int N = in_sizes[0] / 74;   // 25000
    const int E = in_sizes[1] / 12;   // 50000
    const int G = out_size;           // 1000

    float* ws    = (float*)d_ws;
    float* h     = ws;                         // N*64
    float* msum  = h + (size_t)N * 64;         // N*64
    float* t     = msum + (size_t)N * 64;      // E*64
    unsigned short* w_staged = (unsigned short*)(t + (size_t)E * 64); // 65*8192 B

    // one-time: weight staging (bf16, swizzled, chunk-major)
    prep_w_kernel<<<130, 256, 0, stream>>>(eW2, eb2, w_staged);

    // node projection (GRU hidden init == h) and edge-net first layer
    rowmat_relu_kernel<<<(N + 3) / 4, 256, 0, stream>>>(n_feats, proj_W, proj_b, h, N, 74);
    rowmat_relu_kernel<<<(E + 3) / 4, 256, 0, stream>>>(e_feats, eW1, eb1, t, E, 12);

    // 3 rounds of message passing + GRU
    for (int it = 0; it < 3; ++it) {
        hipMemsetAsync(msum, 0, (size_t)N * 64 * sizeof(float), stream);
        msg_mfma_kernel<<<(E + 63) / 64, 256, 0, stream>>>(t, h, src, dst, w_staged, msum, E);
        gru_kernel<<<(N + 31) / 32, 256, 0, stream>>>(msum, h, gWi, gWh, gbi, gbh, conv_b, N);
    }

    // fused Set2Set (3 iters) + predict head: one block per graph
    set2set_kernel<<<G, 256, 0, stream>>>(h,
                                          lWi0, lWh0, lb0, lWi1, lWh1, lb1, lWi2, lWh2, lb2,
                                          pW, pb, fW, fb, (float*)d_out);
}

// Round 4
// 340.147 us; speedup vs baseline: 13.5045x; 1.6123x over previous
//
#include <hip/hip_runtime.h>
#include <math.h>

__device__ __forceinline__ float sigf(float x) { return 1.f / (1.f + expf(-x)); }

using half8v = __attribute__((ext_vector_type(8))) _Float16;
using f32x4  = __attribute__((ext_vector_type(4))) float;
using f32x16 = __attribute__((ext_vector_type(16))) float;

__device__ __forceinline__ unsigned short f2h(float x) {
    union { _Float16 h; unsigned short u; } c; c.h = (_Float16)x; return c.u;
}

// ---------------------------------------------------------------------------
// out32/out16[r][c] = relu(sum_k in[r][k]*W[k][c] + b[c]); f32 + f16 copies.
// ---------------------------------------------------------------------------
__global__ __launch_bounds__(256)
void rowmat_relu_fh(const float* __restrict__ in, const float* __restrict__ W,
                    const float* __restrict__ b, float* __restrict__ out32,
                    _Float16* __restrict__ out16, int R, int K)
{
    const int lane = threadIdx.x & 63;
    const int row  = blockIdx.x * 4 + (threadIdx.x >> 6);
    if (row >= R) return;
    const float* inr = in + (size_t)row * K;
    float acc = b[lane];
    for (int k = 0; k < K; ++k)
        acc = fmaf(inr[k], W[(size_t)k * 64 + lane], acc);
    float v = fmaxf(acc, 0.f);
    out32[(size_t)row * 64 + lane] = v;
    out16[(size_t)row * 64 + lane] = (_Float16)v;
}

// f16-only output variant (edge-net first layer: only msg consumes it)
__global__ __launch_bounds__(256)
void rowmat_relu_h(const float* __restrict__ in, const float* __restrict__ W,
                   const float* __restrict__ b, _Float16* __restrict__ out16,
                   int R, int K)
{
    const int lane = threadIdx.x & 63;
    const int row  = blockIdx.x * 4 + (threadIdx.x >> 6);
    if (row >= R) return;
    const float* inr = in + (size_t)row * K;
    float acc = b[lane];
    for (int k = 0; k < K; ++k)
        acc = fmaf(inr[k], W[(size_t)k * 64 + lane], acc);
    out16[(size_t)row * 64 + lane] = (_Float16)fmaxf(acc, 0.f);
}

// ---------------------------------------------------------------------------
// One-time weight prep (f16): chunk-major swizzled staging of
//   M[j][o], j in [0,4160): j<4096 -> eW2[j][o]; j>=4096 -> eb2 row (t==1).
// Chunk kc: 16B slot (o,seg) at byte (o*128+seg*16)^((o&7)<<4), 8 f16 each.
// ---------------------------------------------------------------------------
__global__ __launch_bounds__(256)
void prep_w_kernel(const float* __restrict__ eW2, const float* __restrict__ eb2,
                   unsigned short* __restrict__ w_staged)
{
    int slot = blockIdx.x * 256 + threadIdx.x;     // 65*512 slots
    if (slot >= 65 * 512) return;
    int kc  = slot >> 9;
    int s   = slot & 511;
    int o   = s >> 3, seg = s & 7;
    unsigned int packed[4];
    #pragma unroll
    for (int p = 0; p < 4; ++p) {
        int j0 = kc * 64 + seg * 8 + p * 2;
        float v0 = (j0     < 4096) ? eW2[(size_t)j0 * 64 + o]       : eb2[(size_t)(j0 - 4096) * 64 + o];
        float v1 = (j0 + 1 < 4096) ? eW2[(size_t)(j0 + 1) * 64 + o] : eb2[(size_t)(j0 + 1 - 4096) * 64 + o];
        packed[p] = (unsigned int)f2h(v0) | ((unsigned int)f2h(v1) << 16);
    }
    int dstb = ((o * 128) + seg * 16) ^ ((o & 7) << 4);
    uint4 st = {packed[0], packed[1], packed[2], packed[3]};
    *(uint4*)((char*)w_staged + (size_t)kc * 8192 + dstb) = st;
}

// ---------------------------------------------------------------------------
// One-time GRU weight prep: WiT/WhT[n][k] = (f16) W[k*192+n], n<192, k<64.
// ---------------------------------------------------------------------------
__global__ __launch_bounds__(256)
void prep_gruw_kernel(const float* __restrict__ Wi, const float* __restrict__ Wh,
                      _Float16* __restrict__ WiT, _Float16* __restrict__ WhT)
{
    int idx = blockIdx.x * 256 + threadIdx.x;
    if (idx >= 2 * 12288) return;
    const float* W = (idx < 12288) ? Wi : Wh;
    _Float16*    O = (idx < 12288) ? WiT : WhT;
    int r = idx & 12287;
    int n = r >> 6, k = r & 63;
    O[n * 64 + k] = (_Float16)W[(size_t)k * 192 + n];
}

// ---------------------------------------------------------------------------
// MFMA NNConv message (f16):
//   msg[e][o] = sum_{kc} sum_i (t[e][kc] or 1)*h[src[e]][i] * M[kc*64+i][o]
// A-frag = t-scalar (f16) * resident h16 row -> 4 v_pk_mul_f16 per MFMA.
// ---------------------------------------------------------------------------
__global__ __launch_bounds__(256, 4)
void msg_mfma_kernel(const _Float16* __restrict__ t16, const _Float16* __restrict__ h16,
                     const int* __restrict__ src, const int* __restrict__ dst,
                     const unsigned short* __restrict__ w_staged,
                     float* __restrict__ msum, int E)
{
    __shared__ _Float16 tS[64 * 70];                          // [k][e+pad]
    __shared__ __align__(16) unsigned short bbuf[2][4096];    // 2 x 8KB chunks

    const int tid  = threadIdx.x;
    const int lane = tid & 63;
    const int wave = tid >> 6;
    const int wm   = wave & 1, wn = wave >> 1;
    const int e0   = blockIdx.x * 64;

    // stage t tile transposed into tS[k][e] (f16)
    #pragma unroll
    for (int p = 0; p < 2; ++p) {
        int slot = tid + p * 256;               // 0..511
        int e = slot >> 3, k0 = (slot & 7) * 8;
        int ee = e0 + e;
        half8v tv8 = (half8v)(_Float16)0.f;
        if (ee < E) tv8 = ((const half8v*)(t16 + (size_t)ee * 64))[slot & 7];
        #pragma unroll
        for (int j = 0; j < 8; ++j)
            tS[(k0 + j) * 70 + e] = tv8[j];
    }

    // resident h16 row: edge = e0 + wm*32 + (lane&31); k-half = (lane>>5)*8
    const int erow = wm * 32 + (lane & 31);
    const int ee   = e0 + erow;
    const int sidx = (ee < E) ? src[ee] : 0;
    const half8v* hp = (const half8v*)(h16 + (size_t)sidx * 64);
    half8v Hh[4];
    #pragma unroll
    for (int s = 0; s < 4; ++s)
        Hh[s] = hp[s * 2 + (lane >> 5)];

    // prologue: stage chunk 0
    const uint4* wsrc = (const uint4*)w_staged;
    uint4 stg0 = wsrc[tid];
    uint4 stg1 = wsrc[256 + tid];
    ((uint4*)bbuf[0])[tid]       = stg0;
    ((uint4*)bbuf[0])[256 + tid] = stg1;

    f32x16 acc;
    #pragma unroll
    for (int r = 0; r < 16; ++r) acc[r] = 0.f;

    const int colg  = wn * 32 + (lane & 31);
    const int bbase = (colg * 128) ^ ((colg & 7) << 4);

    for (int kc = 0; kc < 65; ++kc) {
        const int cur = kc & 1;
        if (kc < 64) {
            stg0 = wsrc[(size_t)(kc + 1) * 512 + tid];
            stg1 = wsrc[(size_t)(kc + 1) * 512 + 256 + tid];
        }
        __syncthreads();   // bbuf[cur] ready

        const _Float16 tv = (kc < 64) ? tS[kc * 70 + erow] : (_Float16)1.0f;
        const char* bb = (const char*)bbuf[cur];
        #pragma unroll
        for (int s = 0; s < 4; ++s) {
            half8v af = Hh[s] * tv;   // 4 x v_pk_mul_f16
            half8v bf = *(const half8v*)(bb + (bbase + s * 32 + (lane >> 5) * 16));
            acc = __builtin_amdgcn_mfma_f32_32x32x16_f16(af, bf, acc, 0, 0, 0);
        }
        __syncthreads();   // all waves done with bbuf[cur^1]
        if (kc < 64) {
            const int nxt = (kc + 1) & 1;
            ((uint4*)bbuf[nxt])[tid]       = stg0;
            ((uint4*)bbuf[nxt])[256 + tid] = stg1;
        }
    }

    // C/D layout: col=lane&31, row=(r&3)+8*(r>>2)+4*(lane>>5)
    #pragma unroll
    for (int r = 0; r < 16; ++r) {
        const int row  = (r & 3) + 8 * (r >> 2) + 4 * (lane >> 5);
        const int edge = e0 + wm * 32 + row;
        if (edge < E)
            atomicAdd(&msum[(size_t)dst[edge] * 64 + colg], acc[r]);
    }
}

// ---------------------------------------------------------------------------
// MFMA GRU: gi = m@Wi, gh = h@Wh via 16x16x32 f16 MFMA (weights LDS-staged);
// gate math f32 in-register; h (f32) and h16 updated in place.
// Block: 256 thr / 4 waves, 64 rows; wave w owns rows w*16..w*16+15, all 192
// gate cols for both i and h (24 acc tiles).
// ---------------------------------------------------------------------------
__global__ __launch_bounds__(256, 2)
void gru_mfma_kernel(const float* __restrict__ msum, float* __restrict__ h,
                     _Float16* __restrict__ h16,
                     const _Float16* __restrict__ WiT, const _Float16* __restrict__ WhT,
                     const float* __restrict__ bi, const float* __restrict__ bh,
                     const float* __restrict__ conv_b, int N)
{
    __shared__ _Float16 BtI[192 * 72];   // [n][k+pad]
    __shared__ _Float16 BtH[192 * 72];
    __shared__ _Float16 Am[64 * 72];     // [row][k+pad]  m = relu(msum+conv_b)
    __shared__ _Float16 Ah[64 * 72];     // [row][k+pad]  h16

    const int tid  = threadIdx.x;
    const int lane = tid & 63;
    const int wave = tid >> 6;
    const int m0   = wave * 16;
    const int row0 = blockIdx.x * 64;

    // stage WiT/WhT (linear -> padded rows)
    #pragma unroll
    for (int p = 0; p < 6; ++p) {
        int slot = tid + p * 256;            // 0..1535
        int n = slot >> 3, k0 = (slot & 7) * 8;
        uint4 vi = ((const uint4*)WiT)[slot];
        uint4 vh = ((const uint4*)WhT)[slot];
        *(uint4*)&BtI[n * 72 + k0] = vi;
        *(uint4*)&BtH[n * 72 + k0] = vh;
    }
    // stage A tiles: m = relu(msum+conv_b) f32->f16; h from h16
    #pragma unroll
    for (int p = 0; p < 4; ++p) {
        int idx = tid + p * 256;             // 0..1023
        int r = idx >> 4, k4 = (idx & 15) * 4;
        int row = row0 + r;
        float4 mv = make_float4(0.f, 0.f, 0.f, 0.f);
        if (row < N) mv = *(const float4*)&msum[(size_t)row * 64 + k4];
        float4 cb = *(const float4*)&conv_b[k4];
        union { _Float16 hx[4]; uint2 u2; } pk;
        pk.hx[0] = (_Float16)fmaxf(mv.x + cb.x, 0.f);
        pk.hx[1] = (_Float16)fmaxf(mv.y + cb.y, 0.f);
        pk.hx[2] = (_Float16)fmaxf(mv.z + cb.z, 0.f);
        pk.hx[3] = (_Float16)fmaxf(mv.w + cb.w, 0.f);
        *(uint2*)&Am[r * 72 + k4] = pk.u2;
    }
    #pragma unroll
    for (int p = 0; p < 2; ++p) {
        int idx = tid + p * 256;             // 0..511
        int r = idx >> 3, k0 = (idx & 7) * 8;
        int row = row0 + r;
        uint4 v = {0u, 0u, 0u, 0u};
        if (row < N) v = *(const uint4*)&h16[(size_t)row * 64 + k0];
        *(uint4*)&Ah[r * 72 + k0] = v;
    }
    __syncthreads();

    const int l15 = lane & 15;

    f32x4 acc_i[12], acc_h[12];
    #pragma unroll
    for (int nt = 0; nt < 12; ++nt) {
        #pragma unroll
        for (int j = 0; j < 4; ++j) { acc_i[nt][j] = 0.f; acc_h[nt][j] = 0.f; }
    }

    #pragma unroll
    for (int ks = 0; ks < 2; ++ks) {
        const int ka = ks * 32 + (lane >> 4) * 8;
        half8v am = *(const half8v*)&Am[(m0 + l15) * 72 + ka];
        half8v ah = *(const half8v*)&Ah[(m0 + l15) * 72 + ka];
        #pragma unroll
        for (int nt = 0; nt < 12; ++nt) {
            half8v b_i = *(const half8v*)&BtI[(nt * 16 + l15) * 72 + ka];
            half8v b_h = *(const half8v*)&BtH[(nt * 16 + l15) * 72 + ka];
            acc_i[nt] = __builtin_amdgcn_mfma_f32_16x16x32_f16(am, b_i, acc_i[nt], 0, 0, 0);
            acc_h[nt] = __builtin_amdgcn_mfma_f32_16x16x32_f16(ah, b_h, acc_h[nt], 0, 0, 0);
        }
    }

    // epilogue: C layout col=lane&15, row=(lane>>4)*4+j
    const int rgrp = lane >> 4;
    #pragma unroll
    for (int nt0 = 0; nt0 < 4; ++nt0) {
        const int c = nt0 * 16 + l15;
        const float bir = bi[c],        bhr = bh[c];
        const float biz = bi[64 + c],   bhz = bh[64 + c];
        const float bin = bi[128 + c],  bhn = bh[128 + c];
        #pragma unroll
        for (int j = 0; j < 4; ++j) {
            const int row = row0 + m0 + rgrp * 4 + j;
            if (row >= N) continue;
            float rg = sigf(acc_i[nt0][j]     + bir + acc_h[nt0][j]     + bhr);
            float zg = sigf(acc_i[4 + nt0][j] + biz + acc_h[4 + nt0][j] + bhz);
            float ng = tanhf(acc_i[8 + nt0][j] + bin + rg * (acc_h[8 + nt0][j] + bhn));
            float hold = h[(size_t)row * 64 + c];
            float hv = (1.f - zg) * ng + zg * hold;
            h[(size_t)row * 64 + c]   = hv;
            h16[(size_t)row * 64 + c] = (_Float16)hv;
        }
    }
}

// ---------------------------------------------------------------------------
// Fully fused Set2Set (3 iters x 3-layer LSTM + attention) + predict head.
// One 256-thread block per graph (unchanged from round 3).
// ---------------------------------------------------------------------------
__global__ __launch_bounds__(256)
void set2set_kernel(const float* __restrict__ h,
                    const float* __restrict__ lWi0, const float* __restrict__ lWh0, const float* __restrict__ lb0,
                    const float* __restrict__ lWi1, const float* __restrict__ lWh1, const float* __restrict__ lb1,
                    const float* __restrict__ lWi2, const float* __restrict__ lWh2, const float* __restrict__ lb2,
                    const float* __restrict__ pW, const float* __restrict__ pb,
                    const float* __restrict__ fW, const float* __restrict__ fb,
                    float* __restrict__ out)
{
    const int g   = blockIdx.x;
    const int tid = threadIdx.x;

    __shared__ float hl[25 * 65];
    __shared__ float hs[3][64], cs[3][64];
    __shared__ float qstar[128];
    __shared__ float gates[256];
    __shared__ float als[32];

    for (int idx = tid; idx < 25 * 64; idx += 256) {
        int n = idx >> 6, d = idx & 63;
        hl[n * 65 + d] = h[((size_t)g * 25 + n) * 64 + d];
    }
    if (tid < 128) qstar[tid] = 0.f;
    if (tid < 64) {
        #pragma unroll
        for (int l = 0; l < 3; ++l) { hs[l][tid] = 0.f; cs[l][tid] = 0.f; }
    }
    __syncthreads();

    const float* Wis[3] = {lWi0, lWi1, lWi2};
    const float* Whs[3] = {lWh0, lWh1, lWh2};
    const float* bs[3]  = {lb0, lb1, lb2};

    for (int it = 0; it < 3; ++it) {
        #pragma unroll
        for (int l = 0; l < 3; ++l) {
            float acc = bs[l][tid];
            if (l == 0) {
                #pragma unroll 8
                for (int k = 0; k < 128; ++k)
                    acc = fmaf(qstar[k], lWi0[(size_t)k * 256 + tid], acc);
            } else {
                const float* x  = hs[l - 1];
                const float* Wi = Wis[l];
                #pragma unroll 8
                for (int k = 0; k < 64; ++k)
                    acc = fmaf(x[k], Wi[(size_t)k * 256 + tid], acc);
            }
            const float* Wh = Whs[l];
            #pragma unroll 8
            for (int k = 0; k < 64; ++k)
                acc = fmaf(hs[l][k], Wh[(size_t)k * 256 + tid], acc);
            gates[tid] = acc;
            __syncthreads();
            if (tid < 64) {
                float ig = sigf(gates[tid]);
                float fg = sigf(gates[64 + tid]);
                float gg = tanhf(gates[128 + tid]);
                float og = sigf(gates[192 + tid]);
                float cv = fg * cs[l][tid] + ig * gg;
                cs[l][tid] = cv;
                hs[l][tid] = og * tanhf(cv);
            }
            __syncthreads();
        }
        float ev = -1e30f;
        if (tid < 25) {
            float acc = 0.f;
            for (int d = 0; d < 64; ++d)
                acc = fmaf(hl[tid * 65 + d], hs[2][d], acc);
            ev = acc;
        }
        if (tid < 64) {
            float mx = ev;
            #pragma unroll
            for (int off = 16; off; off >>= 1) mx = fmaxf(mx, __shfl_xor(mx, off, 32));
            float ex = (tid < 25) ? expf(ev - mx) : 0.f;
            float sm = ex;
            #pragma unroll
            for (int off = 16; off; off >>= 1) sm += __shfl_xor(sm, off, 32);
            if (tid < 25) als[tid] = ex / sm;
        }
        __syncthreads();
        if (tid < 64) {
            float rdt = 0.f;
            #pragma unroll
            for (int n = 0; n < 25; ++n) rdt = fmaf(als[n], hl[n * 65 + tid], rdt);
            qstar[tid]      = hs[2][tid];
            qstar[64 + tid] = rdt;
        }
        __syncthreads();
    }

    if (tid < 64) {
        float acc = pb[tid];
        #pragma unroll 8
        for (int k = 0; k < 128; ++k)
            acc = fmaf(qstar[k], pW[(size_t)k * 64 + tid], acc);
        float part = fmaxf(acc, 0.f) * fW[tid];
        #pragma unroll
        for (int off = 32; off; off >>= 1) part += __shfl_xor(part, off, 64);
        if (tid == 0) out[g] = 1.f / (1.f + expf(-(part + fb[0])));
    }
}

// ---------------------------------------------------------------------------
extern "C" void kernel_launch(void* const* d_in, const int* in_sizes, int n_in,
                              void* d_out, int out_size, void* d_ws, size_t ws_size,
                              hipStream_t stream)
{
    const float* n_feats = (const float*)d_in[0];
    const float* e_feats = (const float*)d_in[1];
    const int*   src     = (const int*)d_in[2];
    const int*   dst     = (const int*)d_in[3];
    const float* proj_W  = (const float*)d_in[5];
    const float* proj_b  = (const float*)d_in[6];
    const float* eW1     = (const float*)d_in[7];
    const float* eb1     = (const float*)d_in[8];
    const float* eW2     = (const float*)d_in[9];
    const float* eb2     = (const float*)d_in[10];
    const float* conv_b  = (const float*)d_in[11];
    const float* gWi     = (const float*)d_in[12];
    const float* gWh     = (const float*)d_in[13];
    const float* gbi     = (const float*)d_in[14];
    const float* gbh     = (const float*)d_in[15];
    const float* lWi0    = (const float*)d_in[16];
    const float* lWh0    = (const float*)d_in[17];
    const float* lb0     = (const float*)d_in[18];
    const float* lWi1    = (const float*)d_in[19];
    const float* lWh1    = (const float*)d_in[20];
    const float* lb1     = (const float*)d_in[21];
    const float* lWi2    = (const float*)d_in[22];
    const float* lWh2    = (const float*)d_in[23];
    const float* lb2     = (const float*)d_in[24];
    const float* pW      = (const float*)d_in[25];
    const float* pb      = (const float*)d_in[26];
    const float* fW      = (const float*)d_in[27];
    const float* fb      = (const float*)d_in[28];

    const int N = in_sizes[0] / 74;   // 25000
    const int E = in_sizes[1] / 12;   // 50000
    const int G = out_size;           // 1000

    float* ws   = (float*)d_ws;
    float* h    = ws;                             // N*64 f32
    float* msum = h + (size_t)N * 64;             // N*64 f32
    _Float16* h16 = (_Float16*)(msum + (size_t)N * 64);   // N*64 f16
    _Float16* t16 = h16 + (size_t)N * 64;                 // E*64 f16
    unsigned short* w_staged = (unsigned short*)(t16 + (size_t)E * 64); // 65*8192 B
    _Float16* WiT = (_Float16*)(w_staged + 65 * 4096);    // 192*64 f16
    _Float16* WhT = WiT + 12288;                           // 192*64 f16

    // one-time weight prep
    prep_w_kernel<<<130, 256, 0, stream>>>(eW2, eb2, w_staged);
    prep_gruw_kernel<<<96, 256, 0, stream>>>(gWi, gWh, WiT, WhT);

    // node projection (h f32 + f16) and edge-net first layer (f16)
    rowmat_relu_fh<<<(N + 3) / 4, 256, 0, stream>>>(n_feats, proj_W, proj_b, h, h16, N, 74);
    rowmat_relu_h<<<(E + 3) / 4, 256, 0, stream>>>(e_feats, eW1, eb1, t16, E, 12);

    // 3 rounds of message passing + GRU
    for (int it = 0; it < 3; ++it) {
        hipMemsetAsync(msum, 0, (size_t)N * 64 * sizeof(float), stream);
        msg_mfma_kernel<<<(E + 63) / 64, 256, 0, stream>>>(t16, h16, src, dst, w_staged, msum, E);
        gru_mfma_kernel<<<(N + 63) / 64, 256, 0, stream>>>(msum, h, h16, WiT, WhT,
                                                           gbi, gbh, conv_b, N);
    }

    // fused Set2Set (3 iters) + predict head: one block per graph
    set2set_kernel<<<G, 256, 0, stream>>>(h,
                                          lWi0, lWh0, lb0, lWi1, lWh1, lb1, lWi2, lWh2, lb2,
                                          pW, pb, fW, fb, (float*)d_out);
}